// Round 8
// baseline (170.838 us; speedup 1.0000x reference)
//
#include <hip/hip_runtime.h>
#include <math.h>

// PyramidROIAlign: B=2, N=1000, C=256, POOL=7x7
// p3: [2,128,128,256], p4: [2,64,64,256], p5: [2,32,32,256], all fp32 NHWC.
// Output: [2,1000,7,7,256] fp32.
//
// R10: concurrency experiment. Cross-round invariant: every healthy config
// (R2, R9, even R7's spill) moves total TCC traffic at ~4.0 TB/s while the
// write-only fill hits 6.5 -> either a mixed gather+stream BW wall (T-BW)
// or a concurrency cap (T-LAT: VGPR-throttled ~4 loads in flight/wave x
// only 17.6 resident waves/CU, L3 poison-evicted so every fetch ~900cy).
// Decisive test: 1 wave = 1 block. grid = 2000*7; wave = (box, iy).
// 64-thr blocks give full 32-wave/CU residency (448-thr blocks capped at
// 4x7=28 waves + scheduling quantization -> 17.6 measured), each wave an
// independent depth-2 load stream. box = bid/7 keeps a box's 7 waves
// temporally adjacent (L3 catches cross-wave corner sharing).
// If T-LAT: dur -> ~42-50us. If T-BW: dur unchanged ~60 -> declare roofline.
//
// Per-wave: lane covers 4 channels (vec4); depth-2 software pipeline over
// the 7 pool columns: load column ix+1's 4 corners while blending/storing
// column ix. Vector liveness ~8 f4 + pointers -> fits 64-VGPR tier
// (8 waves/SIMD).

#define N_PER_B 1000
#define NBOX    2000   // B*N
#define CCH     256
#define PH      7
#define PW      7

typedef float f4 __attribute__((ext_vector_type(4)));

__global__ __launch_bounds__(64, 8) void pyramid_roi_align_kernel(
    const float* __restrict__ boxes,   // [2000,4] y1,x1,y2,x2
    const float* __restrict__ p3,      // [2,128,128,256]
    const float* __restrict__ p4,      // [2,64,64,256]
    const float* __restrict__ p5,      // [2,32,32,256]
    float* __restrict__ out)           // [2000,49,256]
{
    const int bid  = blockIdx.x;
    const int box  = bid / PH;           // magic-mul div by 7
    const int iy   = bid - box * PH;     // pool row 0..6
    const int lane = threadIdx.x;        // 0..63
    const int c    = lane * 4;

    // ---- per-box setup (wave-uniform -> scalarized) ----
    const f4 bx = *(const f4*)(boxes + box * 4);
    const float y1 = bx.x;
    const float x1 = bx.y;
    const float y2 = bx.z;
    const float x2 = bx.w;
    const float h  = y2 - y1;
    const float w  = x2 - x1;

    // roi_level = clip(ceil(5 + log(h*w)/log(2)), 3, 5) -- match ref op order
    const float lvl  = ceilf(5.0f + logf(h * w) / 0.69314718055994530942f);
    const float lvlc = fminf(fmaxf(lvl, 3.0f), 5.0f);
    const int level  = (int)lvlc;

    const float* feat;
    int H;
    if (level <= 3)      { feat = p3; H = 128; }
    else if (level == 4) { feat = p4; H = 64;  }
    else                 { feat = p5; H = 32;  }
    const int W = H;

    const int b = (box >= N_PER_B) ? 1 : 0;
    feat += (size_t)b * H * W * CCH;

    const float Hm1 = (float)(H - 1);
    const float Wm1 = (float)(W - 1);

    // ---- y geometry (wave-uniform) ----
    // ys = y1*(H-1) + iy * ((y2-y1)*(H-1)/6)   (match reference exactly)
    const float ys = y1 * Hm1 + (float)iy * (h * Hm1 / 6.0f);
    const bool  vy = (ys >= 0.0f) && (ys <= Hm1);

    const float y0f = floorf(ys);
    const float wy  = ys - y0f;
    const float omwy = 1.0f - wy;

    const int y0i = (int)fminf(fmaxf(y0f,        0.0f), Hm1);
    const int y1i = (int)fminf(fmaxf(y0f + 1.0f, 0.0f), Hm1);

    const float* row0 = feat + (size_t)y0i * W * CCH + c;  // top row
    const float* row1 = feat + (size_t)y1i * W * CCH + c;  // bottom row

    const float xstep = w * Wm1 / 6.0f;
    float* dst = out + ((size_t)box * (PH * PW) + (size_t)iy * PW) * CCH + c;

    // Column geometry (wave-uniform): element offsets into a feature row.
    auto colx = [&](int ix, int& off0, int& off1, float& wx, bool& vxv) {
        const float xs = x1 * Wm1 + (float)ix * xstep;
        vxv = (xs >= 0.0f) && (xs <= Wm1);
        const float x0f = floorf(xs);
        wx  = xs - x0f;
        off0 = (int)fminf(fmaxf(x0f,        0.0f), Wm1) * CCH;
        off1 = (int)fminf(fmaxf(x0f + 1.0f, 0.0f), Wm1) * CCH;
    };

    // ---- depth-2 software pipeline over the 7 columns ----
    int   o0, o1;  float wx;  bool vx;
    colx(0, o0, o1, wx, vx);
    f4 a00 = *(const f4*)(row0 + o0);
    f4 a01 = *(const f4*)(row0 + o1);
    f4 a10 = *(const f4*)(row1 + o0);
    f4 a11 = *(const f4*)(row1 + o1);

#pragma unroll
    for (int ix = 0; ix < PW; ++ix) {
        int   n0 = 0, n1 = 0;  float wxn = 0.0f;  bool vxn = false;
        f4 b00, b01, b10, b11;
        if (ix + 1 < PW) {
            colx(ix + 1, n0, n1, wxn, vxn);
            b00 = *(const f4*)(row0 + n0);
            b01 = *(const f4*)(row0 + n1);
            b10 = *(const f4*)(row1 + n0);
            b11 = *(const f4*)(row1 + n1);
        }

        const float omwx = 1.0f - wx;
        f4 res = (a00 * omwx + a01 * wx) * omwy
               + (a10 * omwx + a11 * wx) * wy;
        if (!(vy && vx)) res = (f4)(0.0f);
        *(f4*)(dst + (size_t)ix * CCH) = res;

        if (ix + 1 < PW) {
            a00 = b00; a01 = b01; a10 = b10; a11 = b11;
            wx = wxn; vx = vxn;
        }
    }
}

extern "C" void kernel_launch(void* const* d_in, const int* in_sizes, int n_in,
                              void* d_out, int out_size, void* d_ws, size_t ws_size,
                              hipStream_t stream) {
    const float* boxes = (const float*)d_in[0];
    // d_in[1] = positive_indices (unused by reference)
    const float* p3 = (const float*)d_in[2];
    const float* p4 = (const float*)d_in[3];
    const float* p5 = (const float*)d_in[4];
    // d_in[5] = config (unused)
    float* out = (float*)d_out;

    hipLaunchKernelGGL(pyramid_roi_align_kernel, dim3(NBOX * PH), dim3(64), 0, stream,
                       boxes, p3, p4, p5, out);
}